// Round 18
// baseline (403.901 us; speedup 1.0000x reference)
//
#include <hip/hip_runtime.h>
#include <hip/hip_bf16.h>
#include <math.h>

#define NLAYER 3
#define LREADx 512
#define NSEQx  96

typedef _Float16 f16x8 __attribute__((ext_vector_type(8)));
typedef _Float16 f16x4 __attribute__((ext_vector_type(4)));
typedef _Float16 f16x2 __attribute__((ext_vector_type(2)));
typedef float    f32x4 __attribute__((ext_vector_type(4)));

__device__ __forceinline__ float fsigmoid(float v){ return 1.f/(1.f+__expf(-v)); }
__device__ __forceinline__ float fsoftplus(float v){ return fmaxf(v,0.f) + __logf(1.f + __expf(-fabsf(v))); }

__device__ __forceinline__ unsigned short f2h(float f){
  _Float16 h = (_Float16)f;
  return *reinterpret_cast<unsigned short*>(&h);
}

template<int CTRL>
__device__ __forceinline__ float dpp_add(float v){
  int x = __builtin_amdgcn_update_dpp(0, __float_as_int(v), CTRL, 0xF, 0xF, true);
  return v + __int_as_float(x);
}

// ---------------- expander: h = reads @ ew.T + eb (f16 out, 4 outputs/thread) ----------------
__global__ __launch_bounds__(256) void k_exp(const float* __restrict__ reads,
    const float* __restrict__ ew, const float* __restrict__ eb, _Float16* __restrict__ h){
  int idx = blockIdx.x*256 + threadIdx.x;     // 65536 rows x 16 d-quads
  int dq = idx & 15;
  int row = idx >> 4;
  float4 r4 = *(const float4*)(reads + (size_t)row*4);
  f16x4 o;
  #pragma unroll
  for (int e=0;e<4;e++){
    int d = dq*4 + e;
    float4 w4 = *(const float4*)(ew + d*4);
    o[e] = (_Float16)fmaf(r4.x,w4.x, fmaf(r4.y,w4.y, fmaf(r4.z,w4.z, fmaf(r4.w,w4.w, eb[d]))));
  }
  *(f16x4*)(h + (size_t)row*64 + dq*4) = o;
}

// ---------------- weight f32 -> f16 conversion (inw / ow / xw-padded) ----------------
__global__ __launch_bounds__(256) void k_wcvt(const float* __restrict__ inw,
    const float* __restrict__ ow, const float* __restrict__ xw,
    unsigned short* __restrict__ whf, unsigned short* __restrict__ owh,
    unsigned short* __restrict__ xwh){
  int i = blockIdx.x*256 + threadIdx.x;
  if (i < 49152){ whf[i] = f2h(inw[i]); return; }
  i -= 49152;
  if (i < 24576){ owh[i] = f2h(ow[i]); return; }
  i -= 24576;
  if (i < 18432){
    int l = i / 6144, rem = i % 6144;
    int r = rem >> 7, c = rem & 127;
    xwh[i] = (r < 36) ? f2h(xw[(l*36 + r)*128 + c]) : (unsigned short)0;
  }
}

// ---------------- fused in_proj (MFMA f16) + causal conv(k=4) + silu + z-gate ----------------
__global__ __launch_bounds__(256) void k_xzc(const _Float16* __restrict__ h,
    const unsigned short* __restrict__ wb, const float* __restrict__ cw,
    const float* __restrict__ cb, _Float16* __restrict__ x, _Float16* __restrict__ zsil){
  __shared__ _Float16 hs_[80][68];
  __shared__ _Float16 xp[67][132];
  int t = threadIdx.x;
  int row0 = blockIdx.x*64;
  int l0 = row0 & 511;
  for (int i=t; i<640; i+=256){                 // 80 rows x 8 chunks of 8 halves
    int r = i >> 3, q = i & 7;
    f16x8 v;
    #pragma unroll
    for (int e=0;e<8;e++) v[e] = (_Float16)0.f;
    if (!(l0==0 && r<16)) v = *(const f16x8*)(h + (size_t)(row0-16+r)*64 + q*8);
    *(f16x8*)&hs_[r][q*8] = v;
  }
  int w  = __builtin_amdgcn_readfirstlane(t >> 6);
  int ln = t & 63;
  int lr = ln & 15;
  int lk = (ln >> 4)*8;
  f16x8 bf[4][2];
  #pragma unroll
  for (int ct=0; ct<4; ct++)
    #pragma unroll
    for (int ks=0; ks<2; ks++)
      bf[ct][ks] = *(const f16x8*)(wb + (size_t)(w*64 + ct*16 + lr)*64 + ks*32 + lk);
  __syncthreads();
  f32x4 acc[5][4];
  #pragma unroll
  for (int m=0;m<5;m++)
    #pragma unroll
    for (int ct=0;ct<4;ct++) acc[m][ct] = (f32x4){0.f,0.f,0.f,0.f};
  #pragma unroll
  for (int m=0; m<5; m++){
    f16x8 a0 = *(const f16x8*)&hs_[m*16+lr][lk];
    f16x8 a1 = *(const f16x8*)&hs_[m*16+lr][32 + lk];
    #pragma unroll
    for (int ct=0; ct<4; ct++){
      acc[m][ct] = __builtin_amdgcn_mfma_f32_16x16x32_f16(a0, bf[ct][0], acc[m][ct], 0, 0, 0);
      acc[m][ct] = __builtin_amdgcn_mfma_f32_16x16x32_f16(a1, bf[ct][1], acc[m][ct], 0, 0, 0);
    }
  }
  int colb = w*64;
  #pragma unroll
  for (int m=0; m<5; m++)
    #pragma unroll
    for (int ct=0; ct<4; ct++){
      int col = colb + ct*16 + lr;
      #pragma unroll
      for (int rg=0; rg<4; rg++){
        int rl = m*16 + (ln>>4)*4 + rg;
        float v = acc[m][ct][rg];
        if (col < 128){
          if (rl >= 13) xp[rl-13][col] = (_Float16)v;
        } else {
          if (rl >= 16) zsil[(size_t)(row0 + rl - 16)*128 + (col-128)] = (_Float16)(v * fsigmoid(v));
        }
      }
    }
  __syncthreads();
  int c = t & 127, half = t >> 7;
  float4 w4 = *(const float4*)(cw + c*4);
  float bv = cb[c];
  #pragma unroll
  for (int r=half*32; r<half*32+32; r++){
    float a = fmaf((float)xp[r][c],w4.x, fmaf((float)xp[r+1][c],w4.y,
              fmaf((float)xp[r+2][c],w4.z, fmaf((float)xp[r+3][c],w4.w, bv))));
    x[(size_t)(row0+r)*128 + c] = (_Float16)(a * fsigmoid(a));
  }
}

// ---------------- x_proj (MFMA f16, N padded 48) + dt softplus + B/C interleave (bc f16) ----------------
__global__ __launch_bounds__(256) void k_xd(const _Float16* __restrict__ x,
    const unsigned short* __restrict__ xwh, const float* __restrict__ dtw,
    const float* __restrict__ dtb, float* __restrict__ dt, _Float16* __restrict__ bc){
  __shared__ _Float16 xst[64][136];
  __shared__ float xdl[64][37];
  int t = threadIdx.x;
  int row0 = blockIdx.x*64;
  for (int i=t; i<1024; i+=256){
    int r = i >> 4, q = i & 15;
    *(f16x8*)&xst[r][q*8] = *(const f16x8*)(x + (size_t)(row0+r)*128 + q*8);
  }
  __syncthreads();
  int w = __builtin_amdgcn_readfirstlane(t >> 6);
  int ln = t & 63, lr = ln & 15, kg = ln >> 4;
  f16x8 af[4];
  #pragma unroll
  for (int ks=0; ks<4; ks++) af[ks] = *(const f16x8*)&xst[w*16+lr][ks*32 + kg*8];
  f32x4 acc[3];
  #pragma unroll
  for (int ct=0;ct<3;ct++) acc[ct] = (f32x4){0.f,0.f,0.f,0.f};
  #pragma unroll
  for (int ks=0; ks<4; ks++)
    #pragma unroll
    for (int ct=0; ct<3; ct++){
      f16x8 b = *(const f16x8*)(xwh + (size_t)(ct*16 + lr)*128 + ks*32 + kg*8);
      acc[ct] = __builtin_amdgcn_mfma_f32_16x16x32_f16(af[ks], b, acc[ct], 0, 0, 0);
    }
  #pragma unroll
  for (int ct=0; ct<3; ct++){
    int c = ct*16 + lr;
    if (c < 36){
      #pragma unroll
      for (int rg=0; rg<4; rg++) xdl[w*16 + kg*4 + rg][c] = acc[ct][rg];
    }
  }
  __syncthreads();
  int d = t & 127, half = t >> 7;
  float4 w4 = *(const float4*)(dtw + d*4);
  float bv = dtb[d];
  size_t r0 = (size_t)blockIdx.x*64;
  for (int rr=half; rr<64; rr+=2){
    float v = fmaf(xdl[rr][0],w4.x, fmaf(xdl[rr][1],w4.y, fmaf(xdl[rr][2],w4.z,
              fmaf(xdl[rr][3],w4.w, bv))));
    dt[(r0+rr)*128 + d] = fsoftplus(v);
  }
  for (int i=t; i<2048; i+=256){
    int r = i >> 5, cc = i & 31;
    float vv = (cc & 1) ? xdl[r][20 + (cc>>1)] : xdl[r][4 + (cc>>1)];
    bc[(r0+r)*32 + cc] = (_Float16)vv;
  }
}

// ---------------- selective scan: 16 lanes/d, 1 n/lane, 4 blocks/CU ----------------
// block = (b, d-group of 16); thread = (dl 0..15, n 0..15). Full 16-lane DPP reduce.
// Same double-buffer skeleton: {dt,dtx} f32 pairs + bc f16 staged, ys dbuf, 1 barrier/chunk.
__global__ __launch_bounds__(256) void k_scan(const float* __restrict__ dt,
    const _Float16* __restrict__ x, const _Float16* __restrict__ zsil,
    const _Float16* __restrict__ bc, const float* __restrict__ alog,
    const float* __restrict__ Dp, _Float16* __restrict__ y){
  __shared__ float    dtxb[2][64*36];
  __shared__ _Float16 bcb [2][2048];
  __shared__ float    ys  [2][1024];
  int t = threadIdx.x;
  int b  = blockIdx.x & 127;          // same b -> same XCD (128%8==0)
  int dg = blockIdx.x >> 7;           // 0..7
  int dl = t >> 4;                    // 0..15
  int n  = t & 15;
  int d  = dg*16 + dl;
  float aL = -__expf(alog[d*16 + n]) * 1.44269504f;
  float hs = 0.f;
  size_t base  = (size_t)b*512*128 + (size_t)dg*16;
  size_t baseb = (size_t)b*512*32;
  int ls = t >> 2;                    // staging row 0..63
  int q  = t & 3;                     // staging d-quad / seg
  const float*    dtA = dt   + base  + (size_t)ls*128 + q*4;
  const _Float16* xA  = x    + base  + (size_t)ls*128 + q*4;
  const _Float16* zA  = zsil + base  + (size_t)ls*128 + q*4;
  const _Float16* bA  = bc   + baseb + (size_t)ls*32  + q*8;
  float4 Dv4 = *(const float4*)(Dp + dg*16 + q*4);

  auto stage = [&](int bsel, float4 pd, f16x4 px, f16x8 pbh){
    float4 w0 = make_float4(pd.x, pd.x*(float)px[0], pd.y, pd.y*(float)px[1]);
    float4 w1 = make_float4(pd.z, pd.z*(float)px[2], pd.w, pd.w*(float)px[3]);
    *(float4*)&dtxb[bsel][ls*36 + 8*q]     = w0;
    *(float4*)&dtxb[bsel][ls*36 + 8*q + 4] = w1;
    *(f16x8*)&bcb[bsel][ls*32 + q*8]       = pbh;
  };

  {
    float4 pd = *(const float4*)(dtA);
    f16x4  px = *(const f16x4*)(xA);
    f16x8  pbh = *(const f16x8*)(bA);
    stage(0, pd, px, pbh);
  }
  asm volatile("s_waitcnt lgkmcnt(0)" ::: "memory");
  __builtin_amdgcn_s_barrier();

  for (int c=0;c<8;c++){
    int buf = c & 1;
    float4 nd;
    f16x4  nx;
    f16x8  nbh;
    if (c < 7){
      nd  = *(const float4*)(dtA + (c+1)*8192);
      nx  = *(const f16x4*)(xA  + (c+1)*8192);
      nbh = *(const f16x8*)(bA  + (c+1)*2048);
    }
    f16x4 xe = *(const f16x4*)(xA + c*8192);
    f16x4 ze = *(const f16x4*)(zA + c*8192);
    #pragma unroll 8
    for (int l=0;l<64;l++){
      float2 dx = *(const float2*)&dtxb[buf][l*36 + 2*dl];
      f16x2 bch = *(const f16x2*)&bcb[buf][l*32 + 2*n];
      float e = __builtin_amdgcn_exp2f(dx.x * aL);
      hs = fmaf(e, hs, dx.y * (float)bch[0]);
      float p = hs * (float)bch[1];
      p = dpp_add<0x101>(p);   // row_shl:1
      p = dpp_add<0x102>(p);   // row_shl:2
      p = dpp_add<0x104>(p);   // row_shl:4
      p = dpp_add<0x108>(p);   // row_shl:8
      if (n == 0) ys[buf][l*16 + dl] = p;
    }
    if (c < 7) stage(buf^1, nd, nx, nbh);
    asm volatile("s_waitcnt lgkmcnt(0)" ::: "memory");
    __builtin_amdgcn_s_barrier();
    // epilogue: thread covers row ls, d-seg q (4 halves)
    size_t yb = base + (size_t)c*8192;
    float4 s = *(const float4*)&ys[buf][ls*16 + q*4];
    f16x4 o;
    o[0] = (_Float16)((s.x + (float)xe[0]*Dv4.x) * (float)ze[0]);
    o[1] = (_Float16)((s.y + (float)xe[1]*Dv4.y) * (float)ze[1]);
    o[2] = (_Float16)((s.z + (float)xe[2]*Dv4.z) * (float)ze[2]);
    o[3] = (_Float16)((s.w + (float)xe[3]*Dv4.w) * (float)ze[3]);
    *(f16x4*)(y + yb + (size_t)ls*128 + q*4) = o;
  }
}

// ---------------- out proj (MFMA f16) + LayerNorm + ReLU ----------------
__global__ __launch_bounds__(256) void k_out(const _Float16* __restrict__ y,
    const unsigned short* __restrict__ owh, const float* __restrict__ lnw,
    const float* __restrict__ lnb, _Float16* __restrict__ h){
  __shared__ _Float16 yst[64][136];
  int t = threadIdx.x;
  int row0 = blockIdx.x*64;
  for (int i=t; i<1024; i+=256){
    int r = i >> 4, q = i & 15;
    *(f16x8*)&yst[r][q*8] = *(const f16x8*)(y + (size_t)(row0+r)*128 + q*8);
  }
  __syncthreads();
  int w = __builtin_amdgcn_readfirstlane(t >> 6);
  int ln = t & 63, lr = ln & 15, kg = ln >> 4;
  f16x8 af[4];
  #pragma unroll
  for (int ks=0; ks<4; ks++) af[ks] = *(const f16x8*)&yst[w*16+lr][ks*32 + kg*8];
  f32x4 acc[4];
  #pragma unroll
  for (int ct=0;ct<4;ct++) acc[ct] = (f32x4){0.f,0.f,0.f,0.f};
  #pragma unroll
  for (int ks=0; ks<4; ks++)
    #pragma unroll
    for (int ct=0; ct<4; ct++){
      f16x8 b = *(const f16x8*)(owh + (size_t)(ct*16 + lr)*128 + ks*32 + kg*8);
      acc[ct] = __builtin_amdgcn_mfma_f32_16x16x32_f16(af[ks], b, acc[ct], 0, 0, 0);
    }
  float mean[4], inv[4];
  #pragma unroll
  for (int rg=0; rg<4; rg++){
    float s = acc[0][rg] + acc[1][rg] + acc[2][rg] + acc[3][rg];
    #pragma unroll
    for (int off=1; off<16; off<<=1) s += __shfl_xor(s, off, 64);
    mean[rg] = s * (1.f/64.f);
  }
  #pragma unroll
  for (int rg=0; rg<4; rg++){
    float v = 0.f;
    #pragma unroll
    for (int ct=0; ct<4; ct++){ float dv = acc[ct][rg]-mean[rg]; v += dv*dv; }
    #pragma unroll
    for (int off=1; off<16; off<<=1) v += __shfl_xor(v, off, 64);
    inv[rg] = rsqrtf(v*(1.f/64.f) + 1e-5f);
  }
  float lw[4], lb[4];
  #pragma unroll
  for (int ct=0; ct<4; ct++){ lw[ct] = lnw[ct*16+lr]; lb[ct] = lnb[ct*16+lr]; }
  #pragma unroll
  for (int rg=0; rg<4; rg++){
    int row = row0 + w*16 + kg*4 + rg;
    #pragma unroll
    for (int ct=0; ct<4; ct++){
      float o = (acc[ct][rg]-mean[rg])*inv[rg]*lw[ct] + lb[ct];
      h[(size_t)row*64 + ct*16 + lr] = (_Float16)fmaxf(o, 0.f);
    }
  }
}

// ---------------- mean + last pooling -> enc (f32) ----------------
__global__ __launch_bounds__(512) void k_pool(const _Float16* __restrict__ h, float* __restrict__ enc){
  __shared__ float ps[8][64];
  int t = threadIdx.x;
  int w = t >> 6, d = t & 63;
  int b = blockIdx.x;
  const _Float16* hb = h + (size_t)b*LREADx*64;
  float s = 0.f;
  #pragma unroll 8
  for (int i=0;i<64;i++) s += (float)hb[(size_t)(w*64+i)*64 + d];
  ps[w][d] = s;
  __syncthreads();
  if (w == 0){
    float acc = 0.f;
    #pragma unroll
    for (int i=0;i<8;i++) acc += ps[i][d];
    enc[b*128 + d]      = acc * (1.f/512.f);
    enc[b*128 + 64 + d] = (float)hb[(size_t)511*64 + d];
  }
}

// ---------------- q,k projections ----------------
__global__ __launch_bounds__(256) void k_qk(const float* __restrict__ enc,
    const int* __restrict__ sidx, const float* __restrict__ qw, const float* __restrict__ qb,
    const float* __restrict__ kw, const float* __restrict__ kb,
    float* __restrict__ qbuf, float* __restrict__ kbuf){
  int idx = blockIdx.x*256 + threadIdx.x;
  if (idx < NSEQx*64){
    int qi = idx >> 6, j = idx & 63;
    const float* er = enc + (size_t)sidx[qi]*128;
    const float* wr = qw + j*128;
    float a = qb[j];
    for (int k=0;k<32;k++){
      float4 e4 = *(const float4*)(er + k*4);
      float4 w4 = *(const float4*)(wr + k*4);
      a = fmaf(e4.x,w4.x, fmaf(e4.y,w4.y, fmaf(e4.z,w4.z, fmaf(e4.w,w4.w, a))));
    }
    qbuf[idx] = a;
  } else {
    int i2 = idx - NSEQx*64;
    int ki = i2 >> 6, j = i2 & 63;
    const float* er = enc + (size_t)ki*128;
    const float* wr = kw + j*128;
    float a = kb[j];
    for (int k=0;k<32;k++){
      float4 e4 = *(const float4*)(er + k*4);
      float4 w4 = *(const float4*)(wr + k*4);
      a = fmaf(e4.x,w4.x, fmaf(e4.y,w4.y, fmaf(e4.z,w4.z, fmaf(e4.w,w4.w, a))));
    }
    kbuf[i2] = a;
  }
}

// ---------------- scores ----------------
__global__ __launch_bounds__(256) void k_score(const float* __restrict__ qbuf,
    const float* __restrict__ kbuf, const float* __restrict__ mixw,
    const float* __restrict__ mixb, float* __restrict__ out){
  int idx = blockIdx.x*256 + threadIdx.x;
  int ki = idx & 127, qi = idx >> 7;
  const float* qr = qbuf + qi*64;
  const float* kr = kbuf + ki*64;
  float s[4];
  #pragma unroll
  for (int hh=0;hh<4;hh++){
    float a = 0.f;
    #pragma unroll
    for (int k=0;k<4;k++){
      float4 q4 = *(const float4*)(qr + hh*16 + k*4);
      float4 k4 = *(const float4*)(kr + hh*16 + k*4);
      a = fmaf(q4.x,k4.x, fmaf(q4.y,k4.y, fmaf(q4.z,k4.z, fmaf(q4.w,k4.w, a))));
    }
    s[hh] = fmaxf(a, 0.f);
  }
  float best = -1e30f;
  #pragma unroll
  for (int hh=0;hh<4;hh++){
    float v = mixb[hh];
    #pragma unroll
    for (int h2=0;h2<4;h2++) v = fmaf(s[h2], mixw[hh*4+h2], v);
    best = fmaxf(best, v);
  }
  out[idx] = best;
}

extern "C" void kernel_launch(void* const* d_in, const int* in_sizes, int n_in,
                              void* d_out, int out_size, void* d_ws, size_t ws_size,
                              hipStream_t stream) {
  (void)in_sizes; (void)n_in; (void)out_size; (void)ws_size;
  const float* reads = (const float*)d_in[0];
  const int*   sidx  = (const int*)d_in[1];
  const float* ew    = (const float*)d_in[2];
  const float* eb    = (const float*)d_in[3];
  const float* inw   = (const float*)d_in[4];
  const float* cw    = (const float*)d_in[5];
  const float* cb    = (const float*)d_in[6];
  const float* xw    = (const float*)d_in[7];
  const float* dtw   = (const float*)d_in[8];
  const float* dtb   = (const float*)d_in[9];
  const float* alog  = (const float*)d_in[10];
  const float* Dp    = (const float*)d_in[11];
  const float* ow    = (const float*)d_in[12];
  const float* lnw   = (const float*)d_in[13];
  const float* lnb   = (const float*)d_in[14];
  const float* qw    = (const float*)d_in[15];
  const float* qb    = (const float*)d_in[16];
  const float* kw    = (const float*)d_in[17];
  const float* kb    = (const float*)d_in[18];
  const float* mixw  = (const float*)d_in[19];
  const float* mixb  = (const float*)d_in[20];

  float* ws  = (float*)d_ws;
  _Float16* h  = (_Float16*)(ws);              // 4M halves
  _Float16* yx = (_Float16*)(ws + 4194304);    // 8M halves
  _Float16* zs = (_Float16*)(ws + 12582912);   // 8M halves
  _Float16* x  = (_Float16*)(ws + 20971520);   // 8M halves
  float* dt  = ws + 29360128;                  // 8,388,608 f32
  _Float16* bc = (_Float16*)(ws + 37748736);   // 2M halves
  float* enc = ws + 39845888;      // 16,384
  float* qk  = ws + 39862272;      // 6144 + 8192
  unsigned short* whf = (unsigned short*)(ws + 39876608);  // 49,152 f16
  unsigned short* owh = whf + 49152;                       // 24,576 f16
  unsigned short* xwh = owh + 24576;                       // 18,432 f16 (padded 48)

  k_wcvt <<<360, 256, 0, stream>>>(inw, ow, xw, whf, owh, xwh);
  k_exp  <<<4096, 256, 0, stream>>>(reads, ew, eb, h);
  for (int l = 0; l < NLAYER; l++){
    k_xzc <<<1024, 256, 0, stream>>>(h, whf + l*16384, cw + l*512, cb + l*128, x, zs);
    k_xd  <<<1024, 256, 0, stream>>>(x, xwh + l*6144, dtw + l*512, dtb + l*128, dt, bc);
    k_scan<<<1024, 256, 0, stream>>>(dt, x, zs, bc, alog + l*2048, Dp + l*128, yx);
    k_out <<<1024, 256, 0, stream>>>(yx, owh + l*8192, lnw + l*64, lnb + l*64, h);
  }
  k_pool <<<128, 512, 0, stream>>>(h, enc);
  k_qk   <<<56, 256, 0, stream>>>(enc, sidx, qw, qb, kw, kb, qk, qk + 6144);
  k_score<<<48, 256, 0, stream>>>(qk, qk + 6144, mixw, mixb, (float*)d_out);
}

// Round 19
// 382.072 us; speedup vs baseline: 1.0571x; 1.0571x over previous
//
#include <hip/hip_runtime.h>
#include <hip/hip_bf16.h>
#include <math.h>

#define NLAYER 3
#define LREADx 512
#define NSEQx  96

typedef _Float16 f16x8 __attribute__((ext_vector_type(8)));
typedef _Float16 f16x4 __attribute__((ext_vector_type(4)));
typedef _Float16 f16x2 __attribute__((ext_vector_type(2)));
typedef float    f32x4 __attribute__((ext_vector_type(4)));

__device__ __forceinline__ float fsigmoid(float v){ return 1.f/(1.f+__expf(-v)); }
__device__ __forceinline__ float fsoftplus(float v){ return fmaxf(v,0.f) + __logf(1.f + __expf(-fabsf(v))); }

__device__ __forceinline__ unsigned short f2h(float f){
  _Float16 h = (_Float16)f;
  return *reinterpret_cast<unsigned short*>(&h);
}

template<int CTRL>
__device__ __forceinline__ float dpp_add(float v){
  int x = __builtin_amdgcn_update_dpp(0, __float_as_int(v), CTRL, 0xF, 0xF, true);
  return v + __int_as_float(x);
}

// ---------------- expander: h = reads @ ew.T + eb (f16 out, 4 outputs/thread) ----------------
__global__ __launch_bounds__(256) void k_exp(const float* __restrict__ reads,
    const float* __restrict__ ew, const float* __restrict__ eb, _Float16* __restrict__ h){
  int idx = blockIdx.x*256 + threadIdx.x;     // 65536 rows x 16 d-quads
  int dq = idx & 15;
  int row = idx >> 4;
  float4 r4 = *(const float4*)(reads + (size_t)row*4);
  f16x4 o;
  #pragma unroll
  for (int e=0;e<4;e++){
    int d = dq*4 + e;
    float4 w4 = *(const float4*)(ew + d*4);
    o[e] = (_Float16)fmaf(r4.x,w4.x, fmaf(r4.y,w4.y, fmaf(r4.z,w4.z, fmaf(r4.w,w4.w, eb[d]))));
  }
  *(f16x4*)(h + (size_t)row*64 + dq*4) = o;
}

// ---------------- weight f32 -> f16 conversion (inw / ow / xw-padded) ----------------
__global__ __launch_bounds__(256) void k_wcvt(const float* __restrict__ inw,
    const float* __restrict__ ow, const float* __restrict__ xw,
    unsigned short* __restrict__ whf, unsigned short* __restrict__ owh,
    unsigned short* __restrict__ xwh){
  int i = blockIdx.x*256 + threadIdx.x;
  if (i < 49152){ whf[i] = f2h(inw[i]); return; }
  i -= 49152;
  if (i < 24576){ owh[i] = f2h(ow[i]); return; }
  i -= 24576;
  if (i < 18432){
    int l = i / 6144, rem = i % 6144;
    int r = rem >> 7, c = rem & 127;
    xwh[i] = (r < 36) ? f2h(xw[(l*36 + r)*128 + c]) : (unsigned short)0;
  }
}

// ---------------- fused in_proj (MFMA f16) + causal conv(k=4) + silu + z-gate ----------------
__global__ __launch_bounds__(256) void k_xzc(const _Float16* __restrict__ h,
    const unsigned short* __restrict__ wb, const float* __restrict__ cw,
    const float* __restrict__ cb, _Float16* __restrict__ x, _Float16* __restrict__ zsil){
  __shared__ _Float16 hs_[80][68];
  __shared__ _Float16 xp[67][132];
  int t = threadIdx.x;
  int row0 = blockIdx.x*64;
  int l0 = row0 & 511;
  for (int i=t; i<640; i+=256){                 // 80 rows x 8 chunks of 8 halves
    int r = i >> 3, q = i & 7;
    f16x8 v;
    #pragma unroll
    for (int e=0;e<8;e++) v[e] = (_Float16)0.f;
    if (!(l0==0 && r<16)) v = *(const f16x8*)(h + (size_t)(row0-16+r)*64 + q*8);
    *(f16x8*)&hs_[r][q*8] = v;
  }
  int w  = __builtin_amdgcn_readfirstlane(t >> 6);
  int ln = t & 63;
  int lr = ln & 15;
  int lk = (ln >> 4)*8;
  f16x8 bf[4][2];
  #pragma unroll
  for (int ct=0; ct<4; ct++)
    #pragma unroll
    for (int ks=0; ks<2; ks++)
      bf[ct][ks] = *(const f16x8*)(wb + (size_t)(w*64 + ct*16 + lr)*64 + ks*32 + lk);
  __syncthreads();
  f32x4 acc[5][4];
  #pragma unroll
  for (int m=0;m<5;m++)
    #pragma unroll
    for (int ct=0;ct<4;ct++) acc[m][ct] = (f32x4){0.f,0.f,0.f,0.f};
  #pragma unroll
  for (int m=0; m<5; m++){
    f16x8 a0 = *(const f16x8*)&hs_[m*16+lr][lk];
    f16x8 a1 = *(const f16x8*)&hs_[m*16+lr][32 + lk];
    #pragma unroll
    for (int ct=0; ct<4; ct++){
      acc[m][ct] = __builtin_amdgcn_mfma_f32_16x16x32_f16(a0, bf[ct][0], acc[m][ct], 0, 0, 0);
      acc[m][ct] = __builtin_amdgcn_mfma_f32_16x16x32_f16(a1, bf[ct][1], acc[m][ct], 0, 0, 0);
    }
  }
  int colb = w*64;
  #pragma unroll
  for (int m=0; m<5; m++)
    #pragma unroll
    for (int ct=0; ct<4; ct++){
      int col = colb + ct*16 + lr;
      #pragma unroll
      for (int rg=0; rg<4; rg++){
        int rl = m*16 + (ln>>4)*4 + rg;
        float v = acc[m][ct][rg];
        if (col < 128){
          if (rl >= 13) xp[rl-13][col] = (_Float16)v;
        } else {
          if (rl >= 16) zsil[(size_t)(row0 + rl - 16)*128 + (col-128)] = (_Float16)(v * fsigmoid(v));
        }
      }
    }
  __syncthreads();
  int c = t & 127, half = t >> 7;
  float4 w4 = *(const float4*)(cw + c*4);
  float bv = cb[c];
  #pragma unroll
  for (int r=half*32; r<half*32+32; r++){
    float a = fmaf((float)xp[r][c],w4.x, fmaf((float)xp[r+1][c],w4.y,
              fmaf((float)xp[r+2][c],w4.z, fmaf((float)xp[r+3][c],w4.w, bv))));
    x[(size_t)(row0+r)*128 + c] = (_Float16)(a * fsigmoid(a));
  }
}

// ---------------- x_proj (MFMA f16, N padded 48) + dt softplus + B/C interleave (bc f16) ----------------
__global__ __launch_bounds__(256) void k_xd(const _Float16* __restrict__ x,
    const unsigned short* __restrict__ xwh, const float* __restrict__ dtw,
    const float* __restrict__ dtb, float* __restrict__ dt, _Float16* __restrict__ bc){
  __shared__ _Float16 xst[64][136];
  __shared__ float xdl[64][37];
  int t = threadIdx.x;
  int row0 = blockIdx.x*64;
  for (int i=t; i<1024; i+=256){
    int r = i >> 4, q = i & 15;
    *(f16x8*)&xst[r][q*8] = *(const f16x8*)(x + (size_t)(row0+r)*128 + q*8);
  }
  __syncthreads();
  int w = __builtin_amdgcn_readfirstlane(t >> 6);
  int ln = t & 63, lr = ln & 15, kg = ln >> 4;
  f16x8 af[4];
  #pragma unroll
  for (int ks=0; ks<4; ks++) af[ks] = *(const f16x8*)&xst[w*16+lr][ks*32 + kg*8];
  f32x4 acc[3];
  #pragma unroll
  for (int ct=0;ct<3;ct++) acc[ct] = (f32x4){0.f,0.f,0.f,0.f};
  #pragma unroll
  for (int ks=0; ks<4; ks++)
    #pragma unroll
    for (int ct=0; ct<3; ct++){
      f16x8 b = *(const f16x8*)(xwh + (size_t)(ct*16 + lr)*128 + ks*32 + kg*8);
      acc[ct] = __builtin_amdgcn_mfma_f32_16x16x32_f16(af[ks], b, acc[ct], 0, 0, 0);
    }
  #pragma unroll
  for (int ct=0; ct<3; ct++){
    int c = ct*16 + lr;
    if (c < 36){
      #pragma unroll
      for (int rg=0; rg<4; rg++) xdl[w*16 + kg*4 + rg][c] = acc[ct][rg];
    }
  }
  __syncthreads();
  int d = t & 127, half = t >> 7;
  float4 w4 = *(const float4*)(dtw + d*4);
  float bv = dtb[d];
  size_t r0 = (size_t)blockIdx.x*64;
  for (int rr=half; rr<64; rr+=2){
    float v = fmaf(xdl[rr][0],w4.x, fmaf(xdl[rr][1],w4.y, fmaf(xdl[rr][2],w4.z,
              fmaf(xdl[rr][3],w4.w, bv))));
    dt[(r0+rr)*128 + d] = fsoftplus(v);
  }
  for (int i=t; i<2048; i+=256){
    int r = i >> 5, cc = i & 31;
    float vv = (cc & 1) ? xdl[r][20 + (cc>>1)] : xdl[r][4 + (cc>>1)];
    bc[(r0+r)*32 + cc] = (_Float16)vv;
  }
}

// ---------------- selective scan: 2 n/lane (work-efficient), ys f16 -> 3 blocks/CU ----------------
__global__ __launch_bounds__(256) void k_scan(const float* __restrict__ dt,
    const _Float16* __restrict__ x, const _Float16* __restrict__ zsil,
    const _Float16* __restrict__ bc, const float* __restrict__ alog,
    const float* __restrict__ Dp, _Float16* __restrict__ y){
  __shared__ float    dtxb[2][64*68];
  __shared__ _Float16 bcb [2][2048];
  __shared__ _Float16 ys  [2][2048];
  int t = threadIdx.x;
  int b  = blockIdx.x & 127;          // same b -> same XCD (128%8==0)
  int dg = blockIdx.x >> 7;           // 0..3
  int dl = t >> 3;                    // 0..31
  int np = t & 7;
  int d  = dg*32 + dl;
  float aL1 = -__expf(alog[d*16 + 2*np])     * 1.44269504f;
  float aL2 = -__expf(alog[d*16 + 2*np + 1]) * 1.44269504f;
  float hs1 = 0.f, hs2 = 0.f;
  size_t base  = (size_t)b*512*128 + (size_t)dg*32;
  size_t baseb = (size_t)b*512*32;
  int r  = t >> 3;                    // dt/x staging row 0..31
  int d0 = (t & 7)*4;                 // staging col
  int rb = t >> 2;                    // bc staging row 0..63
  int cb_ = (t & 3)*8;                // bc staging col (halves)
  const float*    dtA = dt   + base  + (size_t)r*128 + d0;
  const _Float16* xA  = x    + base  + (size_t)r*128 + d0;
  const _Float16* zA  = zsil + base  + (size_t)r*128 + d0;
  const _Float16* bA  = bc   + baseb + (size_t)rb*32 + cb_;
  float4 Dv4 = *(const float4*)(Dp + dg*32 + d0);

  auto stage = [&](int bsel, float4 pd0, float4 pd1, f16x4 px0, f16x4 px1, f16x8 pbh){
    float4 w0 = make_float4(pd0.x, pd0.x*(float)px0[0], pd0.y, pd0.y*(float)px0[1]);
    float4 w1 = make_float4(pd0.z, pd0.z*(float)px0[2], pd0.w, pd0.w*(float)px0[3]);
    float4 w2 = make_float4(pd1.x, pd1.x*(float)px1[0], pd1.y, pd1.y*(float)px1[1]);
    float4 w3 = make_float4(pd1.z, pd1.z*(float)px1[2], pd1.w, pd1.w*(float)px1[3]);
    *(float4*)&dtxb[bsel][r*68 + 2*d0]          = w0;
    *(float4*)&dtxb[bsel][r*68 + 2*d0 + 4]      = w1;
    *(float4*)&dtxb[bsel][(r+32)*68 + 2*d0]     = w2;
    *(float4*)&dtxb[bsel][(r+32)*68 + 2*d0 + 4] = w3;
    *(f16x8*)&bcb[bsel][rb*32 + cb_]            = pbh;
  };

  {
    float4 pd0 = *(const float4*)(dtA);
    float4 pd1 = *(const float4*)(dtA + 4096);
    f16x4  px0 = *(const f16x4*)(xA);
    f16x4  px1 = *(const f16x4*)(xA + 4096);
    f16x8  pbh = *(const f16x8*)(bA);
    stage(0, pd0, pd1, px0, px1, pbh);
  }
  asm volatile("s_waitcnt lgkmcnt(0)" ::: "memory");
  __builtin_amdgcn_s_barrier();

  for (int c=0;c<8;c++){
    int buf = c & 1;
    float4 nd0, nd1;
    f16x4  nx0, nx1;
    f16x8  nbh;
    if (c < 7){
      nd0 = *(const float4*)(dtA + (c+1)*8192);
      nd1 = *(const float4*)(dtA + (c+1)*8192 + 4096);
      nx0 = *(const f16x4*)(xA  + (c+1)*8192);
      nx1 = *(const f16x4*)(xA  + (c+1)*8192 + 4096);
      nbh = *(const f16x8*)(bA  + (c+1)*2048);
    }
    f16x4 xe0 = *(const f16x4*)(xA + c*8192);
    f16x4 xe1 = *(const f16x4*)(xA + c*8192 + 4096);
    f16x4 z0  = *(const f16x4*)(zA + c*8192);
    f16x4 z1  = *(const f16x4*)(zA + c*8192 + 4096);
    #pragma unroll 8
    for (int l=0;l<64;l++){
      float2 dx  = *(const float2*)&dtxb[buf][l*68 + 2*dl];
      f16x4 bch  = *(const f16x4*)&bcb[buf][l*32 + 4*np];
      float e1 = __builtin_amdgcn_exp2f(dx.x * aL1);
      float e2 = __builtin_amdgcn_exp2f(dx.x * aL2);
      hs1 = fmaf(e1, hs1, dx.y * (float)bch[0]);
      hs2 = fmaf(e2, hs2, dx.y * (float)bch[2]);
      float p = fmaf(hs1, (float)bch[1], hs2 * (float)bch[3]);
      p = dpp_add<0x101>(p);   // row_shl:1
      p = dpp_add<0x102>(p);   // row_shl:2
      p = dpp_add<0x104>(p);   // row_shl:4
      if (np == 0) ys[buf][l*32 + dl] = (_Float16)p;
    }
    if (c < 7) stage(buf^1, nd0, nd1, nx0, nx1, nbh);
    asm volatile("s_waitcnt lgkmcnt(0)" ::: "memory");
    __builtin_amdgcn_s_barrier();
    size_t yb = base + (size_t)c*8192;
    f16x4 s0 = *(const f16x4*)&ys[buf][4*t];
    f16x4 s1 = *(const f16x4*)&ys[buf][4*t + 1024];
    f16x4 o0, o1;
    o0[0] = (_Float16)(((float)s0[0] + (float)xe0[0]*Dv4.x) * (float)z0[0]);
    o0[1] = (_Float16)(((float)s0[1] + (float)xe0[1]*Dv4.y) * (float)z0[1]);
    o0[2] = (_Float16)(((float)s0[2] + (float)xe0[2]*Dv4.z) * (float)z0[2]);
    o0[3] = (_Float16)(((float)s0[3] + (float)xe0[3]*Dv4.w) * (float)z0[3]);
    o1[0] = (_Float16)(((float)s1[0] + (float)xe1[0]*Dv4.x) * (float)z1[0]);
    o1[1] = (_Float16)(((float)s1[1] + (float)xe1[1]*Dv4.y) * (float)z1[1]);
    o1[2] = (_Float16)(((float)s1[2] + (float)xe1[2]*Dv4.z) * (float)z1[2]);
    o1[3] = (_Float16)(((float)s1[3] + (float)xe1[3]*Dv4.w) * (float)z1[3]);
    *(f16x4*)(y + yb + (size_t)r*128 + d0)      = o0;
    *(f16x4*)(y + yb + (size_t)(r+32)*128 + d0) = o1;
  }
}

// ---------------- out proj (MFMA f16) + LayerNorm + ReLU ----------------
__global__ __launch_bounds__(256) void k_out(const _Float16* __restrict__ y,
    const unsigned short* __restrict__ owh, const float* __restrict__ lnw,
    const float* __restrict__ lnb, _Float16* __restrict__ h){
  __shared__ _Float16 yst[64][136];
  int t = threadIdx.x;
  int row0 = blockIdx.x*64;
  for (int i=t; i<1024; i+=256){
    int r = i >> 4, q = i & 15;
    *(f16x8*)&yst[r][q*8] = *(const f16x8*)(y + (size_t)(row0+r)*128 + q*8);
  }
  __syncthreads();
  int w = __builtin_amdgcn_readfirstlane(t >> 6);
  int ln = t & 63, lr = ln & 15, kg = ln >> 4;
  f16x8 af[4];
  #pragma unroll
  for (int ks=0; ks<4; ks++) af[ks] = *(const f16x8*)&yst[w*16+lr][ks*32 + kg*8];
  f32x4 acc[4];
  #pragma unroll
  for (int ct=0;ct<4;ct++) acc[ct] = (f32x4){0.f,0.f,0.f,0.f};
  #pragma unroll
  for (int ks=0; ks<4; ks++)
    #pragma unroll
    for (int ct=0; ct<4; ct++){
      f16x8 b = *(const f16x8*)(owh + (size_t)(ct*16 + lr)*128 + ks*32 + kg*8);
      acc[ct] = __builtin_amdgcn_mfma_f32_16x16x32_f16(af[ks], b, acc[ct], 0, 0, 0);
    }
  float mean[4], inv[4];
  #pragma unroll
  for (int rg=0; rg<4; rg++){
    float s = acc[0][rg] + acc[1][rg] + acc[2][rg] + acc[3][rg];
    #pragma unroll
    for (int off=1; off<16; off<<=1) s += __shfl_xor(s, off, 64);
    mean[rg] = s * (1.f/64.f);
  }
  #pragma unroll
  for (int rg=0; rg<4; rg++){
    float v = 0.f;
    #pragma unroll
    for (int ct=0; ct<4; ct++){ float dv = acc[ct][rg]-mean[rg]; v += dv*dv; }
    #pragma unroll
    for (int off=1; off<16; off<<=1) v += __shfl_xor(v, off, 64);
    inv[rg] = rsqrtf(v*(1.f/64.f) + 1e-5f);
  }
  float lw[4], lb[4];
  #pragma unroll
  for (int ct=0; ct<4; ct++){ lw[ct] = lnw[ct*16+lr]; lb[ct] = lnb[ct*16+lr]; }
  #pragma unroll
  for (int rg=0; rg<4; rg++){
    int row = row0 + w*16 + kg*4 + rg;
    #pragma unroll
    for (int ct=0; ct<4; ct++){
      float o = (acc[ct][rg]-mean[rg])*inv[rg]*lw[ct] + lb[ct];
      h[(size_t)row*64 + ct*16 + lr] = (_Float16)fmaxf(o, 0.f);
    }
  }
}

// ---------------- mean + last pooling -> enc (f32) ----------------
__global__ __launch_bounds__(512) void k_pool(const _Float16* __restrict__ h, float* __restrict__ enc){
  __shared__ float ps[8][64];
  int t = threadIdx.x;
  int w = t >> 6, d = t & 63;
  int b = blockIdx.x;
  const _Float16* hb = h + (size_t)b*LREADx*64;
  float s = 0.f;
  #pragma unroll 8
  for (int i=0;i<64;i++) s += (float)hb[(size_t)(w*64+i)*64 + d];
  ps[w][d] = s;
  __syncthreads();
  if (w == 0){
    float acc = 0.f;
    #pragma unroll
    for (int i=0;i<8;i++) acc += ps[i][d];
    enc[b*128 + d]      = acc * (1.f/512.f);
    enc[b*128 + 64 + d] = (float)hb[(size_t)511*64 + d];
  }
}

// ---------------- q,k projections ----------------
__global__ __launch_bounds__(256) void k_qk(const float* __restrict__ enc,
    const int* __restrict__ sidx, const float* __restrict__ qw, const float* __restrict__ qb,
    const float* __restrict__ kw, const float* __restrict__ kb,
    float* __restrict__ qbuf, float* __restrict__ kbuf){
  int idx = blockIdx.x*256 + threadIdx.x;
  if (idx < NSEQx*64){
    int qi = idx >> 6, j = idx & 63;
    const float* er = enc + (size_t)sidx[qi]*128;
    const float* wr = qw + j*128;
    float a = qb[j];
    for (int k=0;k<32;k++){
      float4 e4 = *(const float4*)(er + k*4);
      float4 w4 = *(const float4*)(wr + k*4);
      a = fmaf(e4.x,w4.x, fmaf(e4.y,w4.y, fmaf(e4.z,w4.z, fmaf(e4.w,w4.w, a))));
    }
    qbuf[idx] = a;
  } else {
    int i2 = idx - NSEQx*64;
    int ki = i2 >> 6, j = i2 & 63;
    const float* er = enc + (size_t)ki*128;
    const float* wr = kw + j*128;
    float a = kb[j];
    for (int k=0;k<32;k++){
      float4 e4 = *(const float4*)(er + k*4);
      float4 w4 = *(const float4*)(wr + k*4);
      a = fmaf(e4.x,w4.x, fmaf(e4.y,w4.y, fmaf(e4.z,w4.z, fmaf(e4.w,w4.w, a))));
    }
    kbuf[i2] = a;
  }
}

// ---------------- scores ----------------
__global__ __launch_bounds__(256) void k_score(const float* __restrict__ qbuf,
    const float* __restrict__ kbuf, const float* __restrict__ mixw,
    const float* __restrict__ mixb, float* __restrict__ out){
  int idx = blockIdx.x*256 + threadIdx.x;
  int ki = idx & 127, qi = idx >> 7;
  const float* qr = qbuf + qi*64;
  const float* kr = kbuf + ki*64;
  float s[4];
  #pragma unroll
  for (int hh=0;hh<4;hh++){
    float a = 0.f;
    #pragma unroll
    for (int k=0;k<4;k++){
      float4 q4 = *(const float4*)(qr + hh*16 + k*4);
      float4 k4 = *(const float4*)(kr + hh*16 + k*4);
      a = fmaf(q4.x,k4.x, fmaf(q4.y,k4.y, fmaf(q4.z,k4.z, fmaf(q4.w,k4.w, a))));
    }
    s[hh] = fmaxf(a, 0.f);
  }
  float best = -1e30f;
  #pragma unroll
  for (int hh=0;hh<4;hh++){
    float v = mixb[hh];
    #pragma unroll
    for (int h2=0;h2<4;h2++) v = fmaf(s[h2], mixw[hh*4+h2], v);
    best = fmaxf(best, v);
  }
  out[idx] = best;
}

extern "C" void kernel_launch(void* const* d_in, const int* in_sizes, int n_in,
                              void* d_out, int out_size, void* d_ws, size_t ws_size,
                              hipStream_t stream) {
  (void)in_sizes; (void)n_in; (void)out_size; (void)ws_size;
  const float* reads = (const float*)d_in[0];
  const int*   sidx  = (const int*)d_in[1];
  const float* ew    = (const float*)d_in[2];
  const float* eb    = (const float*)d_in[3];
  const float* inw   = (const float*)d_in[4];
  const float* cw    = (const float*)d_in[5];
  const float* cb    = (const float*)d_in[6];
  const float* xw    = (const float*)d_in[7];
  const float* dtw   = (const float*)d_in[8];
  const float* dtb   = (const float*)d_in[9];
  const float* alog  = (const float*)d_in[10];
  const float* Dp    = (const float*)d_in[11];
  const float* ow    = (const float*)d_in[12];
  const float* lnw   = (const float*)d_in[13];
  const float* lnb   = (const float*)d_in[14];
  const float* qw    = (const float*)d_in[15];
  const float* qb    = (const float*)d_in[16];
  const float* kw    = (const float*)d_in[17];
  const float* kb    = (const float*)d_in[18];
  const float* mixw  = (const float*)d_in[19];
  const float* mixb  = (const float*)d_in[20];

  float* ws  = (float*)d_ws;
  _Float16* h  = (_Float16*)(ws);              // 4M halves
  _Float16* yx = (_Float16*)(ws + 4194304);    // 8M halves
  _Float16* zs = (_Float16*)(ws + 12582912);   // 8M halves
  _Float16* x  = (_Float16*)(ws + 20971520);   // 8M halves
  float* dt  = ws + 29360128;                  // 8,388,608 f32
  _Float16* bc = (_Float16*)(ws + 37748736);   // 2M halves
  float* enc = ws + 39845888;      // 16,384
  float* qk  = ws + 39862272;      // 6144 + 8192
  unsigned short* whf = (unsigned short*)(ws + 39876608);  // 49,152 f16
  unsigned short* owh = whf + 49152;                       // 24,576 f16
  unsigned short* xwh = owh + 24576;                       // 18,432 f16 (padded 48)

  k_wcvt <<<360, 256, 0, stream>>>(inw, ow, xw, whf, owh, xwh);
  k_exp  <<<4096, 256, 0, stream>>>(reads, ew, eb, h);
  for (int l = 0; l < NLAYER; l++){
    k_xzc <<<1024, 256, 0, stream>>>(h, whf + l*16384, cw + l*512, cb + l*128, x, zs);
    k_xd  <<<1024, 256, 0, stream>>>(x, xwh + l*6144, dtw + l*512, dtb + l*128, dt, bc);
    k_scan<<<512, 256, 0, stream>>>(dt, x, zs, bc, alog + l*2048, Dp + l*128, yx);
    k_out <<<1024, 256, 0, stream>>>(yx, owh + l*8192, lnw + l*64, lnb + l*64, h);
  }
  k_pool <<<128, 512, 0, stream>>>(h, enc);
  k_qk   <<<56, 256, 0, stream>>>(enc, sidx, qw, qb, kw, kb, qk, qk + 6144);
  k_score<<<48, 256, 0, stream>>>(qk, qk + 6144, mixw, mixb, (float*)d_out);
}

// Round 20
// 367.987 us; speedup vs baseline: 1.0976x; 1.0383x over previous
//
#include <hip/hip_runtime.h>
#include <hip/hip_bf16.h>
#include <math.h>

#define NLAYER 3
#define LREADx 512
#define NSEQx  96

typedef _Float16 f16x8 __attribute__((ext_vector_type(8)));
typedef _Float16 f16x4 __attribute__((ext_vector_type(4)));
typedef _Float16 f16x2 __attribute__((ext_vector_type(2)));
typedef float    f32x4 __attribute__((ext_vector_type(4)));

__device__ __forceinline__ float fsigmoid(float v){ return 1.f/(1.f+__expf(-v)); }
__device__ __forceinline__ float fsoftplus(float v){ return fmaxf(v,0.f) + __logf(1.f + __expf(-fabsf(v))); }

__device__ __forceinline__ unsigned short f2h(float f){
  _Float16 h = (_Float16)f;
  return *reinterpret_cast<unsigned short*>(&h);
}

template<int CTRL>
__device__ __forceinline__ float dpp_add(float v){
  int x = __builtin_amdgcn_update_dpp(0, __float_as_int(v), CTRL, 0xF, 0xF, true);
  return v + __int_as_float(x);
}

// ---------------- expander: h = reads @ ew.T + eb (f16 out, 4 outputs/thread) ----------------
__global__ __launch_bounds__(256) void k_exp(const float* __restrict__ reads,
    const float* __restrict__ ew, const float* __restrict__ eb, _Float16* __restrict__ h){
  int idx = blockIdx.x*256 + threadIdx.x;     // 65536 rows x 16 d-quads
  int dq = idx & 15;
  int row = idx >> 4;
  float4 r4 = *(const float4*)(reads + (size_t)row*4);
  f16x4 o;
  #pragma unroll
  for (int e=0;e<4;e++){
    int d = dq*4 + e;
    float4 w4 = *(const float4*)(ew + d*4);
    o[e] = (_Float16)fmaf(r4.x,w4.x, fmaf(r4.y,w4.y, fmaf(r4.z,w4.z, fmaf(r4.w,w4.w, eb[d]))));
  }
  *(f16x4*)(h + (size_t)row*64 + dq*4) = o;
}

// ---------------- weight f32 -> f16 conversion (inw / ow / xw-padded) ----------------
__global__ __launch_bounds__(256) void k_wcvt(const float* __restrict__ inw,
    const float* __restrict__ ow, const float* __restrict__ xw,
    unsigned short* __restrict__ whf, unsigned short* __restrict__ owh,
    unsigned short* __restrict__ xwh){
  int i = blockIdx.x*256 + threadIdx.x;
  if (i < 49152){ whf[i] = f2h(inw[i]); return; }
  i -= 49152;
  if (i < 24576){ owh[i] = f2h(ow[i]); return; }
  i -= 24576;
  if (i < 18432){
    int l = i / 6144, rem = i % 6144;
    int r = rem >> 7, c = rem & 127;
    xwh[i] = (r < 36) ? f2h(xw[(l*36 + r)*128 + c]) : (unsigned short)0;
  }
}

// ---------------- fused in_proj (MFMA f16) + causal conv(k=4) + silu + z-gate ----------------
__global__ __launch_bounds__(256) void k_xzc(const _Float16* __restrict__ h,
    const unsigned short* __restrict__ wb, const float* __restrict__ cw,
    const float* __restrict__ cb, _Float16* __restrict__ x, _Float16* __restrict__ zsil){
  __shared__ _Float16 hs_[80][68];
  __shared__ _Float16 xp[67][132];
  int t = threadIdx.x;
  int row0 = blockIdx.x*64;
  int l0 = row0 & 511;
  for (int i=t; i<640; i+=256){                 // 80 rows x 8 chunks of 8 halves
    int r = i >> 3, q = i & 7;
    f16x8 v;
    #pragma unroll
    for (int e=0;e<8;e++) v[e] = (_Float16)0.f;
    if (!(l0==0 && r<16)) v = *(const f16x8*)(h + (size_t)(row0-16+r)*64 + q*8);
    *(f16x8*)&hs_[r][q*8] = v;
  }
  int w  = __builtin_amdgcn_readfirstlane(t >> 6);
  int ln = t & 63;
  int lr = ln & 15;
  int lk = (ln >> 4)*8;
  f16x8 bf[4][2];
  #pragma unroll
  for (int ct=0; ct<4; ct++)
    #pragma unroll
    for (int ks=0; ks<2; ks++)
      bf[ct][ks] = *(const f16x8*)(wb + (size_t)(w*64 + ct*16 + lr)*64 + ks*32 + lk);
  __syncthreads();
  f32x4 acc[5][4];
  #pragma unroll
  for (int m=0;m<5;m++)
    #pragma unroll
    for (int ct=0;ct<4;ct++) acc[m][ct] = (f32x4){0.f,0.f,0.f,0.f};
  #pragma unroll
  for (int m=0; m<5; m++){
    f16x8 a0 = *(const f16x8*)&hs_[m*16+lr][lk];
    f16x8 a1 = *(const f16x8*)&hs_[m*16+lr][32 + lk];
    #pragma unroll
    for (int ct=0; ct<4; ct++){
      acc[m][ct] = __builtin_amdgcn_mfma_f32_16x16x32_f16(a0, bf[ct][0], acc[m][ct], 0, 0, 0);
      acc[m][ct] = __builtin_amdgcn_mfma_f32_16x16x32_f16(a1, bf[ct][1], acc[m][ct], 0, 0, 0);
    }
  }
  int colb = w*64;
  #pragma unroll
  for (int m=0; m<5; m++)
    #pragma unroll
    for (int ct=0; ct<4; ct++){
      int col = colb + ct*16 + lr;
      #pragma unroll
      for (int rg=0; rg<4; rg++){
        int rl = m*16 + (ln>>4)*4 + rg;
        float v = acc[m][ct][rg];
        if (col < 128){
          if (rl >= 13) xp[rl-13][col] = (_Float16)v;
        } else {
          if (rl >= 16) zsil[(size_t)(row0 + rl - 16)*128 + (col-128)] = (_Float16)(v * fsigmoid(v));
        }
      }
    }
  __syncthreads();
  int c = t & 127, half = t >> 7;
  float4 w4 = *(const float4*)(cw + c*4);
  float bv = cb[c];
  #pragma unroll
  for (int r=half*32; r<half*32+32; r++){
    float a = fmaf((float)xp[r][c],w4.x, fmaf((float)xp[r+1][c],w4.y,
              fmaf((float)xp[r+2][c],w4.z, fmaf((float)xp[r+3][c],w4.w, bv))));
    x[(size_t)(row0+r)*128 + c] = (_Float16)(a * fsigmoid(a));
  }
}

// ---------------- x_proj (MFMA f16, N padded 48) + dt softplus + B/C interleave (bc f16) ----------------
__global__ __launch_bounds__(256) void k_xd(const _Float16* __restrict__ x,
    const unsigned short* __restrict__ xwh, const float* __restrict__ dtw,
    const float* __restrict__ dtb, float* __restrict__ dt, _Float16* __restrict__ bc){
  __shared__ _Float16 xst[64][136];
  __shared__ float xdl[64][37];
  int t = threadIdx.x;
  int row0 = blockIdx.x*64;
  for (int i=t; i<1024; i+=256){
    int r = i >> 4, q = i & 15;
    *(f16x8*)&xst[r][q*8] = *(const f16x8*)(x + (size_t)(row0+r)*128 + q*8);
  }
  __syncthreads();
  int w = __builtin_amdgcn_readfirstlane(t >> 6);
  int ln = t & 63, lr = ln & 15, kg = ln >> 4;
  f16x8 af[4];
  #pragma unroll
  for (int ks=0; ks<4; ks++) af[ks] = *(const f16x8*)&xst[w*16+lr][ks*32 + kg*8];
  f32x4 acc[3];
  #pragma unroll
  for (int ct=0;ct<3;ct++) acc[ct] = (f32x4){0.f,0.f,0.f,0.f};
  #pragma unroll
  for (int ks=0; ks<4; ks++)
    #pragma unroll
    for (int ct=0; ct<3; ct++){
      f16x8 b = *(const f16x8*)(xwh + (size_t)(ct*16 + lr)*128 + ks*32 + kg*8);
      acc[ct] = __builtin_amdgcn_mfma_f32_16x16x32_f16(af[ks], b, acc[ct], 0, 0, 0);
    }
  #pragma unroll
  for (int ct=0; ct<3; ct++){
    int c = ct*16 + lr;
    if (c < 36){
      #pragma unroll
      for (int rg=0; rg<4; rg++) xdl[w*16 + kg*4 + rg][c] = acc[ct][rg];
    }
  }
  __syncthreads();
  int d = t & 127, half = t >> 7;
  float4 w4 = *(const float4*)(dtw + d*4);
  float bv = dtb[d];
  size_t r0 = (size_t)blockIdx.x*64;
  for (int rr=half; rr<64; rr+=2){
    float v = fmaf(xdl[rr][0],w4.x, fmaf(xdl[rr][1],w4.y, fmaf(xdl[rr][2],w4.z,
              fmaf(xdl[rr][3],w4.w, bv))));
    dt[(r0+rr)*128 + d] = fsoftplus(v);
  }
  for (int i=t; i<2048; i+=256){
    int r = i >> 5, cc = i & 31;
    float vv = (cc & 1) ? xdl[r][20 + (cc>>1)] : xdl[r][4 + (cc>>1)];
    bc[(r0+r)*32 + cc] = (_Float16)vv;
  }
}

// ---------------- selective scan: {dt,dtx} staged, bc f16, x*D in epilogue ----------------
__global__ __launch_bounds__(256) void k_scan(const float* __restrict__ dt,
    const _Float16* __restrict__ x, const _Float16* __restrict__ zsil,
    const _Float16* __restrict__ bc, const float* __restrict__ alog,
    const float* __restrict__ Dp, _Float16* __restrict__ y){
  __shared__ float    dtxb[2][64*68];
  __shared__ _Float16 bcb [2][2048];
  __shared__ float    ys  [2][2048];
  int t = threadIdx.x;
  int b  = blockIdx.x & 127;          // same b -> same XCD (128%8==0)
  int dg = blockIdx.x >> 7;           // 0..3
  int dl = t >> 3;                    // 0..31
  int np = t & 7;
  int d  = dg*32 + dl;
  float aL1 = -__expf(alog[d*16 + 2*np])     * 1.44269504f;
  float aL2 = -__expf(alog[d*16 + 2*np + 1]) * 1.44269504f;
  float hs1 = 0.f, hs2 = 0.f;
  size_t base  = (size_t)b*512*128 + (size_t)dg*32;
  size_t baseb = (size_t)b*512*32;
  int r  = t >> 3;                    // dt/x staging row 0..31
  int d0 = (t & 7)*4;                 // staging col
  int rb = t >> 2;                    // bc staging row 0..63
  int cb_ = (t & 3)*8;                // bc staging col (halves)
  const float*    dtA = dt   + base  + (size_t)r*128 + d0;
  const _Float16* xA  = x    + base  + (size_t)r*128 + d0;
  const _Float16* zA  = zsil + base  + (size_t)r*128 + d0;
  const _Float16* bA  = bc   + baseb + (size_t)rb*32 + cb_;
  float4 Dv4 = *(const float4*)(Dp + dg*32 + d0);

  auto stage = [&](int bsel, float4 pd0, float4 pd1, f16x4 px0, f16x4 px1, f16x8 pbh){
    float4 w0 = make_float4(pd0.x, pd0.x*(float)px0[0], pd0.y, pd0.y*(float)px0[1]);
    float4 w1 = make_float4(pd0.z, pd0.z*(float)px0[2], pd0.w, pd0.w*(float)px0[3]);
    float4 w2 = make_float4(pd1.x, pd1.x*(float)px1[0], pd1.y, pd1.y*(float)px1[1]);
    float4 w3 = make_float4(pd1.z, pd1.z*(float)px1[2], pd1.w, pd1.w*(float)px1[3]);
    *(float4*)&dtxb[bsel][r*68 + 2*d0]          = w0;
    *(float4*)&dtxb[bsel][r*68 + 2*d0 + 4]      = w1;
    *(float4*)&dtxb[bsel][(r+32)*68 + 2*d0]     = w2;
    *(float4*)&dtxb[bsel][(r+32)*68 + 2*d0 + 4] = w3;
    *(f16x8*)&bcb[bsel][rb*32 + cb_]            = pbh;
  };

  {
    float4 pd0 = *(const float4*)(dtA);
    float4 pd1 = *(const float4*)(dtA + 4096);
    f16x4  px0 = *(const f16x4*)(xA);
    f16x4  px1 = *(const f16x4*)(xA + 4096);
    f16x8  pbh = *(const f16x8*)(bA);
    stage(0, pd0, pd1, px0, px1, pbh);
  }
  asm volatile("s_waitcnt lgkmcnt(0)" ::: "memory");
  __builtin_amdgcn_s_barrier();

  for (int c=0;c<8;c++){
    int buf = c & 1;
    float4 nd0, nd1;
    f16x4  nx0, nx1;
    f16x8  nbh;
    if (c < 7){
      nd0 = *(const float4*)(dtA + (c+1)*8192);
      nd1 = *(const float4*)(dtA + (c+1)*8192 + 4096);
      nx0 = *(const f16x4*)(xA  + (c+1)*8192);
      nx1 = *(const f16x4*)(xA  + (c+1)*8192 + 4096);
      nbh = *(const f16x8*)(bA  + (c+1)*2048);
    }
    f16x4 xe0 = *(const f16x4*)(xA + c*8192);
    f16x4 xe1 = *(const f16x4*)(xA + c*8192 + 4096);
    f16x4 z0  = *(const f16x4*)(zA + c*8192);
    f16x4 z1  = *(const f16x4*)(zA + c*8192 + 4096);
    #pragma unroll 8
    for (int l=0;l<64;l++){
      float2 dx  = *(const float2*)&dtxb[buf][l*68 + 2*dl];
      f16x4 bch  = *(const f16x4*)&bcb[buf][l*32 + 4*np];
      float e1 = __builtin_amdgcn_exp2f(dx.x * aL1);
      float e2 = __builtin_amdgcn_exp2f(dx.x * aL2);
      hs1 = fmaf(e1, hs1, dx.y * (float)bch[0]);
      hs2 = fmaf(e2, hs2, dx.y * (float)bch[2]);
      float p = fmaf(hs1, (float)bch[1], hs2 * (float)bch[3]);
      p = dpp_add<0x101>(p);   // row_shl:1
      p = dpp_add<0x102>(p);   // row_shl:2
      p = dpp_add<0x104>(p);   // row_shl:4
      if (np == 0) ys[buf][l*32 + dl] = p;
    }
    if (c < 7) stage(buf^1, nd0, nd1, nx0, nx1, nbh);
    asm volatile("s_waitcnt lgkmcnt(0)" ::: "memory");
    __builtin_amdgcn_s_barrier();
    size_t yb = base + (size_t)c*8192;
    float4 s0 = *(const float4*)&ys[buf][4*t];
    float4 s1 = *(const float4*)&ys[buf][4*t + 1024];
    f16x4 o0, o1;
    o0[0] = (_Float16)((s0.x + (float)xe0[0]*Dv4.x) * (float)z0[0]);
    o0[1] = (_Float16)((s0.y + (float)xe0[1]*Dv4.y) * (float)z0[1]);
    o0[2] = (_Float16)((s0.z + (float)xe0[2]*Dv4.z) * (float)z0[2]);
    o0[3] = (_Float16)((s0.w + (float)xe0[3]*Dv4.w) * (float)z0[3]);
    o1[0] = (_Float16)((s1.x + (float)xe1[0]*Dv4.x) * (float)z1[0]);
    o1[1] = (_Float16)((s1.y + (float)xe1[1]*Dv4.y) * (float)z1[1]);
    o1[2] = (_Float16)((s1.z + (float)xe1[2]*Dv4.z) * (float)z1[2]);
    o1[3] = (_Float16)((s1.w + (float)xe1[3]*Dv4.w) * (float)z1[3]);
    *(f16x4*)(y + yb + (size_t)r*128 + d0)      = o0;
    *(f16x4*)(y + yb + (size_t)(r+32)*128 + d0) = o1;
  }
}

// ---------------- out proj (MFMA f16) + LayerNorm + ReLU ----------------
__global__ __launch_bounds__(256) void k_out(const _Float16* __restrict__ y,
    const unsigned short* __restrict__ owh, const float* __restrict__ lnw,
    const float* __restrict__ lnb, _Float16* __restrict__ h){
  __shared__ _Float16 yst[64][136];
  int t = threadIdx.x;
  int row0 = blockIdx.x*64;
  for (int i=t; i<1024; i+=256){
    int r = i >> 4, q = i & 15;
    *(f16x8*)&yst[r][q*8] = *(const f16x8*)(y + (size_t)(row0+r)*128 + q*8);
  }
  __syncthreads();
  int w = __builtin_amdgcn_readfirstlane(t >> 6);
  int ln = t & 63, lr = ln & 15, kg = ln >> 4;
  f16x8 af[4];
  #pragma unroll
  for (int ks=0; ks<4; ks++) af[ks] = *(const f16x8*)&yst[w*16+lr][ks*32 + kg*8];
  f32x4 acc[4];
  #pragma unroll
  for (int ct=0;ct<4;ct++) acc[ct] = (f32x4){0.f,0.f,0.f,0.f};
  #pragma unroll
  for (int ks=0; ks<4; ks++)
    #pragma unroll
    for (int ct=0; ct<4; ct++){
      f16x8 b = *(const f16x8*)(owh + (size_t)(ct*16 + lr)*128 + ks*32 + kg*8);
      acc[ct] = __builtin_amdgcn_mfma_f32_16x16x32_f16(af[ks], b, acc[ct], 0, 0, 0);
    }
  float mean[4], inv[4];
  #pragma unroll
  for (int rg=0; rg<4; rg++){
    float s = acc[0][rg] + acc[1][rg] + acc[2][rg] + acc[3][rg];
    #pragma unroll
    for (int off=1; off<16; off<<=1) s += __shfl_xor(s, off, 64);
    mean[rg] = s * (1.f/64.f);
  }
  #pragma unroll
  for (int rg=0; rg<4; rg++){
    float v = 0.f;
    #pragma unroll
    for (int ct=0; ct<4; ct++){ float dv = acc[ct][rg]-mean[rg]; v += dv*dv; }
    #pragma unroll
    for (int off=1; off<16; off<<=1) v += __shfl_xor(v, off, 64);
    inv[rg] = rsqrtf(v*(1.f/64.f) + 1e-5f);
  }
  float lw[4], lb[4];
  #pragma unroll
  for (int ct=0; ct<4; ct++){ lw[ct] = lnw[ct*16+lr]; lb[ct] = lnb[ct*16+lr]; }
  #pragma unroll
  for (int rg=0; rg<4; rg++){
    int row = row0 + w*16 + kg*4 + rg;
    #pragma unroll
    for (int ct=0; ct<4; ct++){
      float o = (acc[ct][rg]-mean[rg])*inv[rg]*lw[ct] + lb[ct];
      h[(size_t)row*64 + ct*16 + lr] = (_Float16)fmaxf(o, 0.f);
    }
  }
}

// ---------------- mean + last pooling -> enc (f32) ----------------
__global__ __launch_bounds__(512) void k_pool(const _Float16* __restrict__ h, float* __restrict__ enc){
  __shared__ float ps[8][64];
  int t = threadIdx.x;
  int w = t >> 6, d = t & 63;
  int b = blockIdx.x;
  const _Float16* hb = h + (size_t)b*LREADx*64;
  float s = 0.f;
  #pragma unroll 8
  for (int i=0;i<64;i++) s += (float)hb[(size_t)(w*64+i)*64 + d];
  ps[w][d] = s;
  __syncthreads();
  if (w == 0){
    float acc = 0.f;
    #pragma unroll
    for (int i=0;i<8;i++) acc += ps[i][d];
    enc[b*128 + d]      = acc * (1.f/512.f);
    enc[b*128 + 64 + d] = (float)hb[(size_t)511*64 + d];
  }
}

// ---------------- q,k projections ----------------
__global__ __launch_bounds__(256) void k_qk(const float* __restrict__ enc,
    const int* __restrict__ sidx, const float* __restrict__ qw, const float* __restrict__ qb,
    const float* __restrict__ kw, const float* __restrict__ kb,
    float* __restrict__ qbuf, float* __restrict__ kbuf){
  int idx = blockIdx.x*256 + threadIdx.x;
  if (idx < NSEQx*64){
    int qi = idx >> 6, j = idx & 63;
    const float* er = enc + (size_t)sidx[qi]*128;
    const float* wr = qw + j*128;
    float a = qb[j];
    for (int k=0;k<32;k++){
      float4 e4 = *(const float4*)(er + k*4);
      float4 w4 = *(const float4*)(wr + k*4);
      a = fmaf(e4.x,w4.x, fmaf(e4.y,w4.y, fmaf(e4.z,w4.z, fmaf(e4.w,w4.w, a))));
    }
    qbuf[idx] = a;
  } else {
    int i2 = idx - NSEQx*64;
    int ki = i2 >> 6, j = i2 & 63;
    const float* er = enc + (size_t)ki*128;
    const float* wr = kw + j*128;
    float a = kb[j];
    for (int k=0;k<32;k++){
      float4 e4 = *(const float4*)(er + k*4);
      float4 w4 = *(const float4*)(wr + k*4);
      a = fmaf(e4.x,w4.x, fmaf(e4.y,w4.y, fmaf(e4.z,w4.z, fmaf(e4.w,w4.w, a))));
    }
    kbuf[i2] = a;
  }
}

// ---------------- scores ----------------
__global__ __launch_bounds__(256) void k_score(const float* __restrict__ qbuf,
    const float* __restrict__ kbuf, const float* __restrict__ mixw,
    const float* __restrict__ mixb, float* __restrict__ out){
  int idx = blockIdx.x*256 + threadIdx.x;
  int ki = idx & 127, qi = idx >> 7;
  const float* qr = qbuf + qi*64;
  const float* kr = kbuf + ki*64;
  float s[4];
  #pragma unroll
  for (int hh=0;hh<4;hh++){
    float a = 0.f;
    #pragma unroll
    for (int k=0;k<4;k++){
      float4 q4 = *(const float4*)(qr + hh*16 + k*4);
      float4 k4 = *(const float4*)(kr + hh*16 + k*4);
      a = fmaf(q4.x,k4.x, fmaf(q4.y,k4.y, fmaf(q4.z,k4.z, fmaf(q4.w,k4.w, a))));
    }
    s[hh] = fmaxf(a, 0.f);
  }
  float best = -1e30f;
  #pragma unroll
  for (int hh=0;hh<4;hh++){
    float v = mixb[hh];
    #pragma unroll
    for (int h2=0;h2<4;h2++) v = fmaf(s[h2], mixw[hh*4+h2], v);
    best = fmaxf(best, v);
  }
  out[idx] = best;
}

extern "C" void kernel_launch(void* const* d_in, const int* in_sizes, int n_in,
                              void* d_out, int out_size, void* d_ws, size_t ws_size,
                              hipStream_t stream) {
  (void)in_sizes; (void)n_in; (void)out_size; (void)ws_size;
  const float* reads = (const float*)d_in[0];
  const int*   sidx  = (const int*)d_in[1];
  const float* ew    = (const float*)d_in[2];
  const float* eb    = (const float*)d_in[3];
  const float* inw   = (const float*)d_in[4];
  const float* cw    = (const float*)d_in[5];
  const float* cb    = (const float*)d_in[6];
  const float* xw    = (const float*)d_in[7];
  const float* dtw   = (const float*)d_in[8];
  const float* dtb   = (const float*)d_in[9];
  const float* alog  = (const float*)d_in[10];
  const float* Dp    = (const float*)d_in[11];
  const float* ow    = (const float*)d_in[12];
  const float* lnw   = (const float*)d_in[13];
  const float* lnb   = (const float*)d_in[14];
  const float* qw    = (const float*)d_in[15];
  const float* qb    = (const float*)d_in[16];
  const float* kw    = (const float*)d_in[17];
  const float* kb    = (const float*)d_in[18];
  const float* mixw  = (const float*)d_in[19];
  const float* mixb  = (const float*)d_in[20];

  float* ws  = (float*)d_ws;
  _Float16* h  = (_Float16*)(ws);              // 4M halves
  _Float16* yx = (_Float16*)(ws + 4194304);    // 8M halves
  _Float16* zs = (_Float16*)(ws + 12582912);   // 8M halves
  _Float16* x  = (_Float16*)(ws + 20971520);   // 8M halves
  float* dt  = ws + 29360128;                  // 8,388,608 f32
  _Float16* bc = (_Float16*)(ws + 37748736);   // 2M halves
  float* enc = ws + 39845888;      // 16,384
  float* qk  = ws + 39862272;      // 6144 + 8192
  unsigned short* whf = (unsigned short*)(ws + 39876608);  // 49,152 f16
  unsigned short* owh = whf + 49152;                       // 24,576 f16
  unsigned short* xwh = owh + 24576;                       // 18,432 f16 (padded 48)

  k_wcvt <<<360, 256, 0, stream>>>(inw, ow, xw, whf, owh, xwh);
  k_exp  <<<4096, 256, 0, stream>>>(reads, ew, eb, h);
  for (int l = 0; l < NLAYER; l++){
    k_xzc <<<1024, 256, 0, stream>>>(h, whf + l*16384, cw + l*512, cb + l*128, x, zs);
    k_xd  <<<1024, 256, 0, stream>>>(x, xwh + l*6144, dtw + l*512, dtb + l*128, dt, bc);
    k_scan<<<512, 256, 0, stream>>>(dt, x, zs, bc, alog + l*2048, Dp + l*128, yx);
    k_out <<<1024, 256, 0, stream>>>(yx, owh + l*8192, lnw + l*64, lnb + l*64, h);
  }
  k_pool <<<128, 512, 0, stream>>>(h, enc);
  k_qk   <<<56, 256, 0, stream>>>(enc, sidx, qw, qb, kw, kb, qk, qk + 6144);
  k_score<<<48, 256, 0, stream>>>(qk, qk + 6144, mixw, mixb, (float*)d_out);
}